// Round 3
// baseline (1025.948 us; speedup 1.0000x reference)
//
#include <hip/hip_runtime.h>
#include <hip/hip_cooperative_groups.h>
#include <math.h>

namespace cg = cooperative_groups;

// Tree: DEPTH=18, N=2^19-1. Children of i: 2i+1, 2i+2. H=E=64, V=26.
//
// Exact algebraic folds:
//   (h1,c1)    = lstm_step(lstm_init, 0, 0)          -- same for every node
//   bias2[r]   = (W_hh@h1)[r] + b_ih[r] + b_hh[r]    -- step-2 constant
//   biasS[r]   = b_ih[r] + b_hh[r]                   -- step-3 bias
//   M          = W_tag @ W_comb[:, :64]
//   tag_e2[v]  = b_tag + W_tag@(b_comb + W_comb[:,64:]@emb[v])
//   node_out(h,v) = log_softmax(M@h + tag_e2[v])
// Memos:
//   memo18[v]         = node_out(h1, v)                    (all 2^18 leaves)
//   memo17[key=26^3]  = node_out(h3(l,r), v)               (all 2^17 nodes)
// Level-16 collapse (FULL path):
//   G1[key] = W_ih @ memo17[key]   (== step-2 preact - bias2, so 1 matvec
//                                    yields both G1 and (h2,c2))
//   G2[key] = W_hh @ h2[key],  c2tab[key]
//   level-16 gates = G1[kR] + G2[kL] + biasS   -- no matvec except M@h3.

#define OFF_H1C1   0
#define OFF_BIAS2  128
#define OFF_BIASS  384
#define OFF_M      640
#define OFF_TAGE2  4736
#define OFF_MEMO18 6400
#define OFF_MEMO17 8064      // 17576*64 -> ends 1132928

// FULL layout (needs 15451008 floats = ~61.8 MB):
//   G1 1132928..5632384, G2 5632384..10131840, C2 10131840..11256704,
//   BUFA 11256704..15451008, BUFB aliases G1 (dead after level 16)
// FALLBACK layout (7576960 floats = ~30.3 MB, proven):
//   H2 1132928..2257792, C2 2257792..3382656, BUFA 3382656..7576960,
//   BUFB aliases H2.
#define FULL_FLOATS 15451008

__device__ __forceinline__ float sigmf(float x){
  return __fdividef(1.0f, 1.0f + __expf(-x));
}
__device__ __forceinline__ float tanhfast(float x){
  float t = __expf(-2.0f * fabsf(x));
  float r = __fdividef(1.0f - t, 1.0f + t);
  return copysignf(r, x);
}
__device__ __forceinline__ float rlane(float v, int k){
  return __int_as_float(__builtin_amdgcn_readlane(__float_as_int(v), k));
}
__device__ __forceinline__ float logsoftmax64(float tag){
  float m = tag;
  #pragma unroll
  for (int s = 32; s >= 1; s >>= 1) m = fmaxf(m, __shfl_xor(m, s, 64));
  float ex = __expf(tag - m);
  float sum = ex;
  #pragma unroll
  for (int s = 32; s >= 1; s >>= 1) sum += __shfl_xor(sum, s, 64);
  return tag - m - __logf(sum);
}

// LDS weight layout: element (row r=g*64+j, col k) at float index
// (k*64 + ((j+k)&63))*4 + g.  Lane j reads float4 slot k*64+((j+k)&63):
// 16 consecutive lanes hit 256B contiguous -> conflict-free b128.
__device__ __forceinline__ void stage_wm(const float* __restrict__ W_ih,
                                         const float* __restrict__ W_hh,
                                         const float* __restrict__ Mw,
                                         float* sWih, float* sWhh, float* sMt){
  for (int idx = threadIdx.x; idx < 16384; idx += blockDim.x){
    int r = idx >> 6, k = idx & 63;
    int j = r & 63,  g = r >> 6;
    int d = (k*64 + ((j + k) & 63))*4 + g;
    sWih[d] = W_ih[idx];
    sWhh[d] = W_hh[idx];
  }
  for (int idx = threadIdx.x; idx < 4096; idx += blockDim.x){
    int jj = idx >> 6, kk = idx & 63;
    sMt[kk*64 + ((jj + kk) & 63)] = Mw[idx];
  }
}

// ---------------- precompute kernel (1 block) ----------------
__global__ __launch_bounds__(256) void k_pre(
    const float* __restrict__ emb,
    const float* __restrict__ W_ih, const float* __restrict__ W_hh,
    const float* __restrict__ b_ih, const float* __restrict__ b_hh,
    const float* __restrict__ W_comb, const float* __restrict__ b_comb,
    const float* __restrict__ W_tag, const float* __restrict__ b_tag,
    const float* __restrict__ lstm_init,
    float* __restrict__ ws)
{
  __shared__ float sWt[4096];
  __shared__ float sWc[8192];
  __shared__ float sg[256];
  __shared__ float sh1[64];
  __shared__ float sceT[64*32];
  __shared__ float sM[4096];
  __shared__ float ste[26*64];
  __shared__ float sth[64];
  int t = threadIdx.x;

  for (int idx = t; idx < 4096; idx += 256) sWt[idx] = W_tag[idx];
  for (int idx = t; idx < 8192; idx += 256) sWc[idx] = W_comb[idx];

  float bsum = b_ih[t] + b_hh[t];
  ws[OFF_BIASS + t] = bsum;
  {
    float acc = bsum;
    for (int k = 0; k < 64; k++) acc = fmaf(W_ih[t*64 + k], lstm_init[k], acc);
    sg[t] = acc;
  }
  __syncthreads();

  if (t < 64){
    float ii = sigmf(sg[t]);
    float gg = tanhfast(sg[128 + t]);
    float oo = sigmf(sg[192 + t]);
    float c = ii * gg;
    float h = oo * tanhfast(c);
    sh1[t] = h;
    ws[OFF_H1C1 + t] = h;
    ws[OFF_H1C1 + 64 + t] = c;
  }
  __syncthreads();

  {
    float acc = bsum;
    for (int k = 0; k < 64; k++) acc = fmaf(W_hh[t*64 + k], sh1[k], acc);
    ws[OFF_BIAS2 + t] = acc;
  }
  for (int idx = t; idx < 26*64; idx += 256){
    int jj = idx / 26, v = idx - jj*26;
    float acc = b_comb[jj];
    for (int e = 0; e < 64; e++) acc = fmaf(sWc[jj*128 + 64 + e], emb[v*64 + e], acc);
    sceT[jj*32 + v] = acc;
  }
  for (int idx = t; idx < 4096; idx += 256){
    int jj = idx >> 6, kk = idx & 63;
    float acc = 0.f;
    for (int m = 0; m < 64; m++) acc = fmaf(sWt[jj*64 + m], sWc[m*128 + kk], acc);
    sM[idx] = acc;
    ws[OFF_M + idx] = acc;
  }
  __syncthreads();
  for (int idx = t; idx < 26*64; idx += 256){
    int jj = idx / 26, v = idx - jj*26;
    float acc = b_tag[jj];
    for (int k = 0; k < 64; k++) acc = fmaf(sWt[jj*64 + k], sceT[k*32 + v], acc);
    ws[OFF_TAGE2 + v*64 + jj] = acc;
    ste[v*64 + jj] = acc;
  }
  if (t < 64){
    float acc = 0.f;
    for (int k = 0; k < 64; k++) acc = fmaf(sM[t*64 + k], sh1[k], acc);
    sth[t] = acc;
  }
  __syncthreads();
  int w = t >> 6, j = t & 63;
  for (int v = w; v < 26; v += 4){
    float tag = sth[j] + ste[v*64 + j];
    ws[OFF_MEMO18 + v*64 + j] = logsoftmax64(tag);
  }
}

// ---------------- the cooperative everything-kernel ----------------
template<int FULL>
__global__ __launch_bounds__(512, 2) void k_main(
    const int* __restrict__ ids,
    const float* __restrict__ W_ih, const float* __restrict__ W_hh,
    float* __restrict__ ws, float* __restrict__ out)
{
  constexpr int OG1   = 1132928;                      // FULL only
  constexpr int OG2   = 5632384;                      // FULL only
  constexpr int OH2   = 1132928;                      // fallback only
  constexpr int OC2   = FULL ? 10131840 : 2257792;
  constexpr int OBUFA = FULL ? 11256704 : 3382656;
  constexpr int OBUFB = 1132928;                      // dead-table alias

  __shared__ float4 sWih4[4096];
  __shared__ float4 sWhh4[4096];
  __shared__ float  sMt[4096];
  stage_wm(W_ih, W_hh, ws + OFF_M, (float*)sWih4, (float*)sWhh4, sMt);
  __syncthreads();

  cg::grid_group grid = cg::this_grid();
  int wv = threadIdx.x >> 6, j = threadIdx.x & 63;
  int gw = blockIdx.x*8 + wv;                         // 0..2047

  float c1  = ws[OFF_H1C1 + 64 + j];
  float b20 = ws[OFF_BIAS2 + j],       b21 = ws[OFF_BIAS2 + 64 + j];
  float b22 = ws[OFF_BIAS2 + 128 + j], b23 = ws[OFF_BIAS2 + 192 + j];
  float bs0 = ws[OFF_BIASS + j],       bs1 = ws[OFF_BIASS + 64 + j];
  float bs2 = ws[OFF_BIASS + 128 + j], bs3 = ws[OFF_BIASS + 192 + j];

  // ---- phase A: memo17 over 676 (lid,rid) pairs ----
  if (gw < 676){
    int lid = gw / 26, rid = gw - lid*26;
    const float* memo18 = ws + OFF_MEMO18;
    float L = memo18[lid*64 + j];
    float R = memo18[rid*64 + j];

    float a0 = b20, a1 = b21, a2 = b22, a3 = b23;
    #pragma unroll 8
    for (int k = 0; k < 64; k++){
      float xk = rlane(L, k);
      float4 w = sWih4[k*64 + ((j + k) & 63)];
      a0 = fmaf(xk, w.x, a0); a1 = fmaf(xk, w.y, a1);
      a2 = fmaf(xk, w.z, a2); a3 = fmaf(xk, w.w, a3);
    }
    float c2 = sigmf(a1)*c1 + sigmf(a0)*tanhfast(a2);
    float h2 = sigmf(a3)*tanhfast(c2);

    a0 = bs0; a1 = bs1; a2 = bs2; a3 = bs3;
    #pragma unroll 8
    for (int k = 0; k < 64; k++){
      float xk = rlane(R, k), hk = rlane(h2, k);
      float4 wi = sWih4[k*64 + ((j + k) & 63)];
      float4 wh = sWhh4[k*64 + ((j + k) & 63)];
      a0 = fmaf(xk, wi.x, fmaf(hk, wh.x, a0));
      a1 = fmaf(xk, wi.y, fmaf(hk, wh.y, a1));
      a2 = fmaf(xk, wi.z, fmaf(hk, wh.z, a2));
      a3 = fmaf(xk, wi.w, fmaf(hk, wh.w, a3));
    }
    float c3 = sigmf(a1)*c2 + sigmf(a0)*tanhfast(a2);
    float h3 = sigmf(a3)*tanhfast(c3);

    float th = 0.f;
    #pragma unroll 8
    for (int k = 0; k < 64; k++)
      th = fmaf(rlane(h3, k), sMt[k*64 + ((j + k) & 63)], th);

    float* m17 = ws + OFF_MEMO17;
    for (int iid = 0; iid < 26; iid++){
      float tag = th + ws[OFF_TAGE2 + iid*64 + j];
      m17[(gw*26 + iid)*64 + j] = logsoftmax64(tag);
    }
  }
  grid.sync();

  // ---- phase B: per-key tables (17576 keys over 2048 waves) ----
  for (int key = gw; key < 17576; key += 2048){
    float L = ws[OFF_MEMO17 + key*64 + j];
    float a0 = 0.f, a1 = 0.f, a2 = 0.f, a3 = 0.f;
    #pragma unroll 8
    for (int k = 0; k < 64; k++){
      float xk = rlane(L, k);
      float4 w = sWih4[k*64 + ((j + k) & 63)];
      a0 = fmaf(xk, w.x, a0); a1 = fmaf(xk, w.y, a1);
      a2 = fmaf(xk, w.z, a2); a3 = fmaf(xk, w.w, a3);
    }
    if (FULL){                       // G1[key] = W_ih @ memo17[key]
      ws[OG1 + key*256 +        j] = a0;
      ws[OG1 + key*256 +  64 +  j] = a1;
      ws[OG1 + key*256 + 128 +  j] = a2;
      ws[OG1 + key*256 + 192 +  j] = a3;
    }
    float g0 = a0 + b20, g1 = a1 + b21, g2 = a2 + b22, g3 = a3 + b23;
    float c2 = sigmf(g1)*c1 + sigmf(g0)*tanhfast(g2);
    float h2 = sigmf(g3)*tanhfast(c2);
    ws[OC2 + key*64 + j] = c2;
    if (FULL){                       // G2[key] = W_hh @ h2
      float e0 = 0.f, e1 = 0.f, e2 = 0.f, e3 = 0.f;
      #pragma unroll 8
      for (int k = 0; k < 64; k++){
        float hk = rlane(h2, k);
        float4 w = sWhh4[k*64 + ((j + k) & 63)];
        e0 = fmaf(hk, w.x, e0); e1 = fmaf(hk, w.y, e1);
        e2 = fmaf(hk, w.z, e2); e3 = fmaf(hk, w.w, e3);
      }
      ws[OG2 + key*256 +        j] = e0;
      ws[OG2 + key*256 +  64 +  j] = e1;
      ws[OG2 + key*256 + 128 +  j] = e2;
      ws[OG2 + key*256 + 192 +  j] = e3;
    } else {
      ws[OH2 + key*64 + j] = h2;
    }
  }
  grid.sync();

  // ---- phase C: level 16 (65536 nodes) -> BUFA ----
  for (int i0 = gw*8; i0 < 65536; i0 += 2048*8){
    float H3[8]; int idv[8];
    #pragma unroll
    for (int t = 0; t < 8; t++){
      int i = i0 + t;
      int m0 = 2*i, m1 = 2*i + 1;
      int kL = (ids[262143 + 2*m0]*26 + ids[262143 + 2*m0 + 1])*26 + ids[131071 + m0];
      int kR = (ids[262143 + 2*m1]*26 + ids[262143 + 2*m1 + 1])*26 + ids[131071 + m1];
      idv[t] = ids[65535 + i];
      float g0, g1, g2, g3, C2v;
      if (FULL){
        const float* p1 = ws + OG1 + kR*256;
        const float* p2 = ws + OG2 + kL*256;
        g0 = p1[j]       + p2[j]       + bs0;
        g1 = p1[64 + j]  + p2[64 + j]  + bs1;
        g2 = p1[128 + j] + p2[128 + j] + bs2;
        g3 = p1[192 + j] + p2[192 + j] + bs3;
        C2v = ws[OC2 + kL*64 + j];
      } else {
        float H2v = ws[OH2 + kL*64 + j];
        C2v = ws[OC2 + kL*64 + j];
        float R = ws[OFF_MEMO17 + kR*64 + j];
        g0 = bs0; g1 = bs1; g2 = bs2; g3 = bs3;
        #pragma unroll 8
        for (int k = 0; k < 64; k++){
          float xk = rlane(R, k), hk = rlane(H2v, k);
          float4 wi = sWih4[k*64 + ((j + k) & 63)];
          float4 wh = sWhh4[k*64 + ((j + k) & 63)];
          g0 = fmaf(xk, wi.x, fmaf(hk, wh.x, g0));
          g1 = fmaf(xk, wi.y, fmaf(hk, wh.y, g1));
          g2 = fmaf(xk, wi.z, fmaf(hk, wh.z, g2));
          g3 = fmaf(xk, wi.w, fmaf(hk, wh.w, g3));
        }
      }
      float c3 = sigmf(g1)*C2v + sigmf(g0)*tanhfast(g2);
      H3[t] = sigmf(g3)*tanhfast(c3);
    }
    float TH[8] = {0.f,0.f,0.f,0.f,0.f,0.f,0.f,0.f};
    #pragma unroll 4
    for (int k = 0; k < 64; k++){
      float mt = sMt[k*64 + ((j + k) & 63)];
      #pragma unroll
      for (int t = 0; t < 8; t++) TH[t] = fmaf(rlane(H3[t], k), mt, TH[t]);
    }
    #pragma unroll
    for (int t = 0; t < 8; t++){
      float tag = TH[t] + ws[OFF_TAGE2 + idv[t]*64 + j];
      ws[OBUFA + (i0 + t)*64 + j] = logsoftmax64(tag);
    }
  }
  grid.sync();

  // ---- phase D: levels 15..0 ----
  const float* prev = ws + OBUFA;
  for (int l = 15; l >= 0; --l){
    int B = 1 << l;
    float* cur = (l == 0) ? out : (ws + ((l & 1) ? OBUFB : OBUFA));

    for (int i0 = gw*8; i0 < B; i0 += 2048*8){
      float L[8], R[8], A0[8], A1[8], A2[8], A3[8];
      #pragma unroll
      for (int t = 0; t < 8; t++){
        int i = i0 + t;
        if (i < B){
          L[t] = prev[(2*i)*64 + j];
          R[t] = prev[(2*i + 1)*64 + j];
        } else { L[t] = 0.f; R[t] = 0.f; }
        A0[t] = b20; A1[t] = b21; A2[t] = b22; A3[t] = b23;
      }
      #pragma unroll 4
      for (int k = 0; k < 64; k++){
        float4 w = sWih4[k*64 + ((j + k) & 63)];
        #pragma unroll
        for (int t = 0; t < 8; t++){
          float xk = rlane(L[t], k);
          A0[t] = fmaf(xk, w.x, A0[t]); A1[t] = fmaf(xk, w.y, A1[t]);
          A2[t] = fmaf(xk, w.z, A2[t]); A3[t] = fmaf(xk, w.w, A3[t]);
        }
      }
      float H2[8], C2[8];
      #pragma unroll
      for (int t = 0; t < 8; t++){
        C2[t] = sigmf(A1[t])*c1 + sigmf(A0[t])*tanhfast(A2[t]);
        H2[t] = sigmf(A3[t])*tanhfast(C2[t]);
        A0[t] = bs0; A1[t] = bs1; A2[t] = bs2; A3[t] = bs3;
      }
      #pragma unroll 4
      for (int k = 0; k < 64; k++){
        float4 wi = sWih4[k*64 + ((j + k) & 63)];
        float4 wh = sWhh4[k*64 + ((j + k) & 63)];
        #pragma unroll
        for (int t = 0; t < 8; t++){
          float xk = rlane(R[t], k), hk = rlane(H2[t], k);
          A0[t] = fmaf(xk, wi.x, fmaf(hk, wh.x, A0[t]));
          A1[t] = fmaf(xk, wi.y, fmaf(hk, wh.y, A1[t]));
          A2[t] = fmaf(xk, wi.z, fmaf(hk, wh.z, A2[t]));
          A3[t] = fmaf(xk, wi.w, fmaf(hk, wh.w, A3[t]));
        }
      }
      float H3[8];
      #pragma unroll
      for (int t = 0; t < 8; t++){
        float c3 = sigmf(A1[t])*C2[t] + sigmf(A0[t])*tanhfast(A2[t]);
        H3[t] = sigmf(A3[t])*tanhfast(c3);
      }
      float TH[8] = {0.f,0.f,0.f,0.f,0.f,0.f,0.f,0.f};
      #pragma unroll 4
      for (int k = 0; k < 64; k++){
        float mt = sMt[k*64 + ((j + k) & 63)];
        #pragma unroll
        for (int t = 0; t < 8; t++) TH[t] = fmaf(rlane(H3[t], k), mt, TH[t]);
      }
      #pragma unroll
      for (int t = 0; t < 8; t++){
        int i = i0 + t;
        if (i < B){
          float tag = TH[t] + ws[OFF_TAGE2 + ids[(B - 1) + i]*64 + j];
          cur[i*64 + j] = logsoftmax64(tag);
        }
      }
    }
    grid.sync();
    prev = cur;
  }
}

extern "C" void kernel_launch(void* const* d_in, const int* in_sizes, int n_in,
                              void* d_out, int out_size, void* d_ws, size_t ws_size,
                              hipStream_t stream)
{
  (void)in_sizes; (void)n_in; (void)out_size;
  const int*   ids    = (const int*)  d_in[0];
  const float* emb    = (const float*)d_in[1];
  const float* W_ih   = (const float*)d_in[2];
  const float* W_hh   = (const float*)d_in[3];
  const float* b_ih   = (const float*)d_in[4];
  const float* b_hh   = (const float*)d_in[5];
  const float* W_comb = (const float*)d_in[6];
  const float* b_comb = (const float*)d_in[7];
  const float* W_tag  = (const float*)d_in[8];
  const float* b_tag  = (const float*)d_in[9];
  const float* linit  = (const float*)d_in[10];
  float* ws  = (float*)d_ws;
  float* out = (float*)d_out;

  k_pre<<<1, 256, 0, stream>>>(emb, W_ih, W_hh, b_ih, b_hh,
                               W_comb, b_comb, W_tag, b_tag, linit, ws);

  void* ka[5];
  ka[0] = (void*)&ids;  ka[1] = (void*)&W_ih; ka[2] = (void*)&W_hh;
  ka[3] = (void*)&ws;   ka[4] = (void*)&out;

  bool full = ws_size >= (size_t)FULL_FLOATS * sizeof(float);
  if (full)
    hipLaunchCooperativeKernel((const void*)k_main<1>, dim3(256), dim3(512),
                               ka, 0, stream);
  else
    hipLaunchCooperativeKernel((const void*)k_main<0>, dim3(256), dim3(512),
                               ka, 0, stream);
}